// Round 1
// baseline (232.044 us; speedup 1.0000x reference)
//
#include <hip/hip_runtime.h>
#include <math.h>

// ive(v=49.5, z) = exp(-z) * I_v(z), computed via the uniform (Debye)
// asymptotic expansion DLMF 10.41.3:
//   I_v(v*x) ~ exp(v*eta) / ( sqrt(2*pi*v) * (1+x^2)^{1/4} ) * sum_k u_k(t)/v^k
//   t = 1/sqrt(1+x^2),  eta = sqrt(1+x^2) + ln( x / (1 + sqrt(1+x^2)) )
// so ive(v,z) = exp(v*eta - z) * sqrt(t) / sqrt(2*pi*v) * poly(t).
// With v=49.5 and terms through u4, truncation error ~ |u5|/v^5 ~ 1e-9
// relative — absolute error << the 4.3e-9 threshold (max|ref| ~ 2.16e-7).
// For small z the exponent is ~-213 -> expf underflows to 0, matching the
// fp32 reference (which also underflows through exp(log_pref)).
//
// Memory-bound kernel: float4 loads/stores, one value per lane per float4 slot.

__device__ __forceinline__ float ive_debye(float z) {
    // compile-time-folded constants
    const float inv_v   = (float)(1.0 / 49.5);
    const float c_pref  = 0.05670319f;                 // 1/sqrt(2*pi*49.5)
    const float c1 = (float)(1.0 / (24.0 * 49.5));
    const float c2 = (float)(1.0 / (1152.0 * 49.5 * 49.5));
    const float c3 = (float)(1.0 / (414720.0 * 49.5 * 49.5 * 49.5));
    const float c4 = (float)(1.0 / (39813120.0 * 49.5 * 49.5 * 49.5 * 49.5));

    float x  = z * inv_v;
    float p  = sqrtf(fmaf(x, x, 1.0f));   // sqrt(1+x^2)
    float t  = 1.0f / p;
    float s  = t * t;

    // eta = p + log(x/(1+p));  exponent = v*eta - z
    float eta = p + logf(x / (1.0f + p));
    float e   = fmaf(49.5f, eta, -z);

    // u_k(t)/v^k, Horner in s=t^2 (A&S 9.3.9 polynomials)
    float u1 = c1 * t * fmaf(-5.0f, s, 3.0f);
    float u2 = c2 * s * fmaf(s, fmaf(385.0f, s, -462.0f), 81.0f);
    float u3 = c3 * (t * s) *
               fmaf(s, fmaf(s, fmaf(-425425.0f, s, 765765.0f), -369603.0f), 30375.0f);
    float u4 = c4 * (s * s) *
               fmaf(s, fmaf(s, fmaf(s, fmaf(185910725.0f, s, -446185740.0f),
                                    349922430.0f), -94121676.0f), 4465125.0f);
    float poly = 1.0f + u1 + u2 + u3 + u4;

    return expf(e) * (c_pref * sqrtf(t)) * poly;
}

__global__ __launch_bounds__(256) void ive_kernel(const float* __restrict__ z,
                                                  float* __restrict__ out,
                                                  int n4, int n) {
    int i = blockIdx.x * blockDim.x + threadIdx.x;
    if (i < n4) {
        float4 zv = ((const float4*)z)[i];
        float4 o;
        o.x = ive_debye(zv.x);
        o.y = ive_debye(zv.y);
        o.z = ive_debye(zv.z);
        o.w = ive_debye(zv.w);
        ((float4*)out)[i] = o;
    }
    // tail (n not divisible by 4): handled by thread 0
    if (i == 0) {
        for (int j = n4 * 4; j < n; ++j) out[j] = ive_debye(z[j]);
    }
}

extern "C" void kernel_launch(void* const* d_in, const int* in_sizes, int n_in,
                              void* d_out, int out_size, void* d_ws, size_t ws_size,
                              hipStream_t stream) {
    const float* z = (const float*)d_in[0];
    float* out = (float*)d_out;
    int n = in_sizes[0];
    int n4 = n >> 2;
    int threads = 256;
    int blocks = (n4 + threads - 1) / threads;
    if (blocks < 1) blocks = 1;
    ive_kernel<<<blocks, threads, 0, stream>>>(z, out, n4, n);
}

// Round 2
// 217.468 us; speedup vs baseline: 1.0670x; 1.0670x over previous
//
#include <hip/hip_runtime.h>
#include <math.h>

// ive(v=49.5, z) = exp(-z) * I_v(z) via the uniform (Debye) asymptotic
// expansion DLMF 10.41.3, worked in log2 domain with gfx950 hardware
// transcendentals (v_rsq/v_rcp/v_log/v_exp/v_sqrt — all ~1 ulp):
//
//   x = z/v, q = 1+x^2, t = 1/sqrt(q), p = sqrt(q)
//   e2 = v*log2e*p + v*log2(x/(1+p)) - log2e*z        (exponent, base 2)
//   ive = exp2(e2) * (1/sqrt(2*pi*v)) * sqrt(t) * sum_k u_k(t)/v^k
//
// Accuracy budget: threshold 4.32e-9 abs vs max|ref| 2.16e-7 -> 2% relative
// at the max. HW intrinsic error after the x49.5 exponent amplification is
// ~1e-5 relative; truncation through u4 is ~1e-9 relative. Huge margin.
// Small z: e2 ~ -300 -> v_exp_f32 flushes to 0, matching the fp32 ref's
// underflow.
//
// R1 counters showed VALUBusy=107%, HBM 2.27 TB/s (28%): the OCML logf/expf
// and IEEE divides were the bottleneck. This version is ~25 FMA + 5
// quarter-rate hw transcendentals per element -> under the ~32 us HBM floor.

__device__ __forceinline__ float ive_debye(float z) {
    const float inv_v    = (float)(1.0 / 49.5);
    const float c_pref   = 0.05670319f;                  // 1/sqrt(2*pi*49.5)
    const float v_log2e  = 71.41340452f;                 // 49.5 * log2(e)
    const float n_log2e  = -1.4426950408889634f;         // -log2(e)
    const float c1 = (float)(1.0 / (24.0 * 49.5));
    const float c2 = (float)(1.0 / (1152.0 * 49.5 * 49.5));
    const float c3 = (float)(1.0 / (414720.0 * 49.5 * 49.5 * 49.5));
    const float c4 = (float)(1.0 / (39813120.0 * 49.5 * 49.5 * 49.5 * 49.5));

    float x = z * inv_v;
    float q = fmaf(x, x, 1.0f);
    float t = __builtin_amdgcn_rsqf(q);       // 1/sqrt(1+x^2)
    float p = q * t;                           // sqrt(1+x^2)
    float s = t * t;

    // log2(x/(1+p)) via hw rcp + hw log2
    float lg = __builtin_amdgcn_logf(x * __builtin_amdgcn_rcpf(1.0f + p));
    // base-2 exponent: v*log2e*p + v*lg - z*log2e
    float e2 = fmaf(v_log2e, p, fmaf(49.5f, lg, n_log2e * z));

    // u_k(t)/v^k, Horner in s=t^2 (A&S 9.3.9)
    float u1 = c1 * t * fmaf(-5.0f, s, 3.0f);
    float u2 = c2 * s * fmaf(s, fmaf(385.0f, s, -462.0f), 81.0f);
    float u3 = c3 * (t * s) *
               fmaf(s, fmaf(s, fmaf(-425425.0f, s, 765765.0f), -369603.0f), 30375.0f);
    float u4 = c4 * (s * s) *
               fmaf(s, fmaf(s, fmaf(s, fmaf(185910725.0f, s, -446185740.0f),
                                    349922430.0f), -94121676.0f), 4465125.0f);
    float poly = 1.0f + u1 + u2 + u3 + u4;

    float pref = c_pref * __builtin_amdgcn_sqrtf(t);
    return __builtin_amdgcn_exp2f(e2) * pref * poly;
}

__global__ __launch_bounds__(256) void ive_kernel(const float* __restrict__ z,
                                                  float* __restrict__ out,
                                                  int n4, int n) {
    int i = blockIdx.x * blockDim.x + threadIdx.x;
    if (i < n4) {
        float4 zv = ((const float4*)z)[i];
        float4 o;
        o.x = ive_debye(zv.x);
        o.y = ive_debye(zv.y);
        o.z = ive_debye(zv.z);
        o.w = ive_debye(zv.w);
        ((float4*)out)[i] = o;
    }
    if (i == 0) {
        for (int j = n4 * 4; j < n; ++j) out[j] = ive_debye(z[j]);
    }
}

extern "C" void kernel_launch(void* const* d_in, const int* in_sizes, int n_in,
                              void* d_out, int out_size, void* d_ws, size_t ws_size,
                              hipStream_t stream) {
    const float* z = (const float*)d_in[0];
    float* out = (float*)d_out;
    int n = in_sizes[0];
    int n4 = n >> 2;
    int threads = 256;
    int blocks = (n4 + threads - 1) / threads;
    if (blocks < 1) blocks = 1;
    ive_kernel<<<blocks, threads, 0, stream>>>(z, out, n4, n);
}